// Round 9
// baseline (1198.513 us; speedup 1.0000x reference)
//
#include <hip/hip_runtime.h>

#define B_TOT 32768
#define NDW 14
#define NSTEPS 30

typedef __attribute__((ext_vector_type(8))) short short8;
typedef __attribute__((ext_vector_type(4))) float f32x4;
typedef __attribute__((ext_vector_type(2))) unsigned int uint2v;

// ---- workspace byte offsets ----
#define WIH_OFF   0           // enc_wih bf16 plain [512][128]
#define WHH_OFF   131072      // enc_whh bf16 plain [512][128]
#define WD_OFF    262144      // dec_wih+dec_whh bf16 plain [512][128]
#define DWHH_OFF  393216      // dec_whh bf16 plain [512][128]
#define FAW_OFF   524288      // fa_w bf16 plain [128][128]
#define WV_OFF    557056      // pooling wv bf16 plain [128][128]
#define WOUT_OFF  589824      // pool_wout bf16 plain [128][128]
#define QK_OFF    622592      // folded q@wk / sqrt(dh), f32 [4][128]
#define EB_OFF    624640      // enc_bih+enc_bhh f32 [512]
#define DB_OFF    626688      // dec_bih+dec_bhh f32 [512]
#define DHW_OFF   628736      // decoder head B-tile bf16 [16][128] (row0=dmu,row1=dsig)
#define TOK_OFF   632832      // monthly token bf16 swizzled tiles [2048][4096]
#define GIN_OFF   9021440     // g_in slots
#define SLOT_BYTES (NDW * 16384)                  // 229376 per 16-row block
// g_in tile layout (16 KiB per (slot,t)): 4 gate planes x 4 KiB; plane g holds
// [pos 0..511] 8B chunks (r0|r1<<16, r2|r3<<16); enc thread tid reads pos=tid.

// ---- enc kernel LDS (15 KiB) ----
#define MH0   0        // h buffer 0 (16 rows x 256B, swizzled bf16)
#define MH1   4096     // h buffer 1
#define MSB   8192     // pooling (rf, e) f32 pairs [16][4]
#define MMD   8704     // pooling denom d f32 [16][4]
#define MXB   11264    // ctx tile bf16 (16 rows x 256B)

// ---- dec kernel LDS (12 KiB): H0 | H1 | MOUT ----
#define DMOUT 8192

__device__ __forceinline__ unsigned short f2bf(float f) {
  unsigned int u = __float_as_uint(f);
  u += 0x7fffu + ((u >> 16) & 1u);
  return (unsigned short)(u >> 16);
}
__device__ __forceinline__ float bf2f(unsigned short h) {
  return __uint_as_float(((unsigned int)h) << 16);
}
__device__ __forceinline__ float sigmf_(float x) { return __builtin_amdgcn_rcpf(1.f + __expf(-x)); }
__device__ __forceinline__ float tanhf_(float x) { return 1.f - 2.f * __builtin_amdgcn_rcpf(1.f + __expf(2.f * x)); }
__device__ __forceinline__ float softplusf_(float x) { return x > 20.f ? x : __logf(1.f + __expf(x)); }
__device__ __forceinline__ int swz(int row, int bc) { return row * 256 + (bc ^ ((row & 7) << 4)); }
__device__ __forceinline__ f32x4 splat4(float v) { f32x4 r = {v, v, v, v}; return r; }
// LDS-only barrier: leaves global (vmcnt) loads in flight across the sync.
__device__ __forceinline__ void bar_lds() {
  asm volatile("s_waitcnt lgkmcnt(0)" ::: "memory");
  __builtin_amdgcn_s_barrier();
  __builtin_amdgcn_sched_barrier(0);
}

// ===================== prep: weight conversion / folding =====================
__global__ void hfn_prep(const float* __restrict__ fa_w,
                         const float* __restrict__ enc_wih, const float* __restrict__ enc_whh,
                         const float* __restrict__ enc_bih, const float* __restrict__ enc_bhh,
                         const float* __restrict__ q_tok,
                         const float* __restrict__ pool_win, const float* __restrict__ pool_bin,
                         const float* __restrict__ pool_wout,
                         const float* __restrict__ dec_wih, const float* __restrict__ dec_whh,
                         const float* __restrict__ dec_bih, const float* __restrict__ dec_bhh,
                         const float* __restrict__ dmu_w, const float* __restrict__ dsig_w,
                         char* __restrict__ ws) {
  const int gt = blockIdx.x * 256 + threadIdx.x;
  const int gs = gridDim.x * 256;
  for (int i = gt; i < 65536; i += gs) *(unsigned short*)(ws + WIH_OFF + 2 * i) = f2bf(enc_wih[i]);
  for (int i = gt; i < 65536; i += gs) *(unsigned short*)(ws + WHH_OFF + 2 * i) = f2bf(enc_whh[i]);
  for (int i = gt; i < 65536; i += gs) *(unsigned short*)(ws + WD_OFF + 2 * i) = f2bf(dec_wih[i] + dec_whh[i]);
  for (int i = gt; i < 65536; i += gs) *(unsigned short*)(ws + DWHH_OFF + 2 * i) = f2bf(dec_whh[i]);
  for (int i = gt; i < 16384; i += gs) *(unsigned short*)(ws + FAW_OFF + 2 * i) = f2bf(fa_w[i]);
  for (int i = gt; i < 16384; i += gs) *(unsigned short*)(ws + WV_OFF + 2 * i) = f2bf(pool_win[32768 + i]);
  for (int i = gt; i < 16384; i += gs) *(unsigned short*)(ws + WOUT_OFF + 2 * i) = f2bf(pool_wout[i]);
  for (int i = gt; i < 512; i += gs) *(float*)(ws + EB_OFF + 4 * i) = enc_bih[i] + enc_bhh[i];
  for (int i = gt; i < 512; i += gs) *(float*)(ws + DB_OFF + 4 * i) = dec_bih[i] + dec_bhh[i];
  for (int i = gt; i < 2048; i += gs) {  // decoder head B-tile
    const int row = i >> 7, k = i & 127;
    const float v = (row == 0) ? dmu_w[k] : ((row == 1) ? dsig_w[k] : 0.f);
    *(unsigned short*)(ws + DHW_OFF + 2 * i) = f2bf(v);
  }
  if (blockIdx.x == 0) {
    __shared__ float q[128];
    const int t = threadIdx.x;
    if (t < 128) {
      float a = 0.f;
      for (int k = 0; k < 128; ++k) a += q_tok[k] * pool_win[t * 128 + k];
      q[t] = a + pool_bin[t];
    }
    __syncthreads();
    for (int j = t; j < 512; j += 256) {
      const int h = j >> 7, kc = j & 127;
      float a = 0.f;
      for (int d = 0; d < 32; ++d) a += q[32 * h + d] * pool_win[(128 + 32 * h + d) * 128 + kc];
      *(float*)(ws + QK_OFF + 4 * j) = a * 0.17677669529663687f;  // bk dropped (softmax-invariant)
    }
  }
}

// ===================== pre-pass: g_in (+bias), 64-row/256-thread blocks =====================
// grid (rows/64, 14); wave w in 0..3 handles rows [16w,16w+16) for attention and owns
// gate-plane w (gate cols [128w,128w+128)) for the gates GEMM. 16 KiB LDS -> 8 blocks/CU.
__global__ __launch_bounds__(256, 8)
void hfn_pre2(const float* __restrict__ x14, const float* __restrict__ fa_b,
              char* __restrict__ ws, int base) {
  __shared__ __align__(16) char sx[16384];
  const int tid = threadIdx.x;
  const int w = tid >> 6, lane = tid & 63, l15 = lane & 15, l4 = lane >> 4;
  const int bx = blockIdx.x;
  const int row0 = base + (bx << 6);
  const int t = blockIdx.y;

  {  // stage x tile (64 rows) f32 -> bf16 swizzled
    const int r = tid >> 2, q = tid & 3;
    const float* src = x14 + ((size_t)(row0 + r) * NDW + t) * 128 + 32 * q;
#pragma unroll
    for (int c = 0; c < 4; ++c) {
      f32x4 v0 = __builtin_nontemporal_load((const f32x4*)(src + 8 * c));
      f32x4 v1 = __builtin_nontemporal_load((const f32x4*)(src + 8 * c + 4));
      short8 s;
#pragma unroll
      for (int e = 0; e < 4; ++e) { s[e] = (short)f2bf(v0[e]); s[e + 4] = (short)f2bf(v1[e]); }
      *(short8*)(sx + swz(r, 64 * q + 16 * c)) = s;
    }
  }
  __syncthreads();
  {  // feature attention in place: wave w handles rows [16w, 16w+16)
    float fbias[8];
#pragma unroll
    for (int nt = 0; nt < 8; ++nt) fbias[nt] = fa_b[16 * nt + l15];
    f32x4 patt[8];
#pragma unroll
    for (int nt = 0; nt < 8; ++nt) patt[nt] = splat4(fbias[nt]);
#pragma unroll
    for (int kk = 0; kk < 4; ++kk) {
      const short8 a = *(const short8*)(sx + swz(16 * w + l15, 64 * kk + 16 * l4));
#pragma unroll
      for (int nt = 0; nt < 8; ++nt) {
        const short8 b = *(const short8*)(ws + FAW_OFF + (16 * nt + l15) * 256 + 64 * kk + 16 * l4);
        patt[nt] = __builtin_amdgcn_mfma_f32_16x16x32_bf16(a, b, patt[nt], 0, 0, 0);
      }
    }
#pragma unroll
    for (int r = 0; r < 4; ++r) {
      float m = patt[0][r];
#pragma unroll
      for (int nt = 1; nt < 8; ++nt) m = fmaxf(m, patt[nt][r]);
      m = fmaxf(m, __shfl_xor(m, 1)); m = fmaxf(m, __shfl_xor(m, 2));
      m = fmaxf(m, __shfl_xor(m, 4)); m = fmaxf(m, __shfl_xor(m, 8));
      float s = 0.f;
#pragma unroll
      for (int nt = 0; nt < 8; ++nt) { const float e = __expf(patt[nt][r] - m); patt[nt][r] = e; s += e; }
      s += __shfl_xor(s, 1); s += __shfl_xor(s, 2); s += __shfl_xor(s, 4); s += __shfl_xor(s, 8);
      const float rs = __builtin_amdgcn_rcpf(s);
      const int row = 16 * w + 4 * l4 + r;
#pragma unroll
      for (int nt = 0; nt < 8; ++nt) {
        const int ad = swz(row, 2 * (16 * nt + l15));
        const float xv = bf2f(*(const unsigned short*)(sx + ad));
        *(unsigned short*)(sx + ad) = f2bf(patt[nt][r] * rs * xv);
      }
    }
  }
  __syncthreads();
  // gates: wave w owns gate plane w (cols [128w,128w+128), nt=0..7); 4 row-subtiles.
  // Store: plane-major nontemporal -> 512B contiguous full lines per wave-store.
  for (int nt = 0; nt < 8; ++nt) {
    const int gcb = 128 * w + 16 * nt;
    const float ebn = *(const float*)(ws + EB_OFF + 4 * (gcb + l15));
    short8 bw[4];
#pragma unroll
    for (int kk = 0; kk < 4; ++kk)
      bw[kk] = *(const short8*)(ws + WIH_OFF + (gcb + l15) * 256 + 64 * kk + 16 * l4);
#pragma unroll
    for (int rt = 0; rt < 4; ++rt) {
      f32x4 acc = splat4(ebn);
#pragma unroll
      for (int kk = 0; kk < 4; ++kk) {
        const short8 a = *(const short8*)(sx + swz(16 * rt + l15, 64 * kk + 16 * l4));
        acc = __builtin_amdgcn_mfma_f32_16x16x32_bf16(a, bw[kk], acc, 0, 0, 0);
      }
      uint2v pk;
      pk[0] = (unsigned int)f2bf(acc[0]) | ((unsigned int)f2bf(acc[1]) << 16);
      pk[1] = (unsigned int)f2bf(acc[2]) | ((unsigned int)f2bf(acc[3]) << 16);
      char* dst = ws + GIN_OFF + (size_t)(4 * bx + rt) * SLOT_BYTES + t * 16384
                + (w << 12) + (((nt << 6) + (l4 << 4) + l15) << 3);
      __builtin_nontemporal_store(pk, (uint2v*)dst);
    }
  }
}

// ===================== encoder kernel: 14 steps + online pooling + daily heads + token =====================
__global__ __launch_bounds__(512, 4)
void hfn_enc(const float* __restrict__ pool_bin, const float* __restrict__ pool_bout,
             const float* __restrict__ mu_w, const float* __restrict__ mu_b,
             const float* __restrict__ sig_w, const float* __restrict__ sig_b,
             char* __restrict__ ws, float* __restrict__ out, int base) {
  __shared__ __align__(16) char sm[15360];
  const int tid = threadIdx.x;
  const int w = tid >> 6, lane = tid & 63, l15 = lane & 15, l4 = lane >> 4;
  const int blkrow = base + (blockIdx.x << 4);

  short8 bhh[4][4];
#pragma unroll
  for (int g = 0; g < 4; ++g)
#pragma unroll
    for (int kk = 0; kk < 4; ++kk)
      bhh[g][kk] = *(const short8*)(ws + WHH_OFF + (g * 128 + 16 * w + l15) * 256 + 64 * kk + 16 * l4);
  float creg[4];
#pragma unroll
  for (int r = 0; r < 4; ++r) creg[r] = 0.f;
  *(uint2*)(sm + MH0 + tid * 8) = make_uint2(0, 0);  // h_{-1} = 0

  const char* ginb = ws + GIN_OFF + (size_t)blockIdx.x * SLOT_BYTES + tid * 8;
  uint2 gp0 = *(const uint2*)(ginb);            // prefetch t=0, planes 0..3
  uint2 gp1 = *(const uint2*)(ginb + 4096);
  uint2 gp2 = *(const uint2*)(ginb + 8192);
  uint2 gp3 = *(const uint2*)(ginb + 12288);
  float mrun = -1e30f, drun = 0.f;
  f32x4 ctx = splat4(0.f);
  bar_lds();

  for (int t = 0; t < NDW; ++t) {
    char* Hr = sm + ((t & 1) ? MH1 : MH0);
    char* Hw = sm + ((t & 1) ? MH0 : MH1);
    const uint2 gc0 = gp0, gc1 = gp1, gc2 = gp2, gc3 = gp3;
    if (t < NDW - 1) {  // prefetch next t; stays in flight across bar_lds
      const char* nb = ginb + (t + 1) * 16384;
      gp0 = *(const uint2*)(nb);
      gp1 = *(const uint2*)(nb + 4096);
      gp2 = *(const uint2*)(nb + 8192);
      gp3 = *(const uint2*)(nb + 12288);
    }
    f32x4 acc[4];
    acc[0][0] = bf2f((unsigned short)(gc0.x & 0xffff)); acc[0][1] = bf2f((unsigned short)(gc0.x >> 16));
    acc[0][2] = bf2f((unsigned short)(gc0.y & 0xffff)); acc[0][3] = bf2f((unsigned short)(gc0.y >> 16));
    acc[1][0] = bf2f((unsigned short)(gc1.x & 0xffff)); acc[1][1] = bf2f((unsigned short)(gc1.x >> 16));
    acc[1][2] = bf2f((unsigned short)(gc1.y & 0xffff)); acc[1][3] = bf2f((unsigned short)(gc1.y >> 16));
    acc[2][0] = bf2f((unsigned short)(gc2.x & 0xffff)); acc[2][1] = bf2f((unsigned short)(gc2.x >> 16));
    acc[2][2] = bf2f((unsigned short)(gc2.y & 0xffff)); acc[2][3] = bf2f((unsigned short)(gc2.y >> 16));
    acc[3][0] = bf2f((unsigned short)(gc3.x & 0xffff)); acc[3][1] = bf2f((unsigned short)(gc3.x >> 16));
    acc[3][2] = bf2f((unsigned short)(gc3.y & 0xffff)); acc[3][3] = bf2f((unsigned short)(gc3.y >> 16));
#pragma unroll
    for (int kk = 0; kk < 4; ++kk) {
      const short8 a = *(const short8*)(Hr + swz(l15, 64 * kk + 16 * l4));
#pragma unroll
      for (int g = 0; g < 4; ++g)
        acc[g] = __builtin_amdgcn_mfma_f32_16x16x32_bf16(a, bhh[g][kk], acc[g], 0, 0, 0);
    }
#pragma unroll
    for (int r = 0; r < 4; ++r) {
      const float cn = sigmf_(acc[1][r]) * creg[r] + sigmf_(acc[0][r]) * tanhf_(acc[2][r]);
      creg[r] = cn;
      *(unsigned short*)(Hw + swz(4 * l4 + r, 2 * (16 * w + l15))) = f2bf(sigmf_(acc[3][r]) * tanhf_(cn));
    }
    bar_lds();
    if (t >= 7) {  // online-softmax pooling update on h_t
      {
        const int rw = tid >> 5, hd = (tid >> 3) & 3, kh = tid & 7;
        const short8 s8a = *(const short8*)(Hw + swz(rw, 32 * kh));
        const short8 s8b = *(const short8*)(Hw + swz(rw, 32 * kh + 16));
        const float* qk = (const float*)(ws + QK_OFF) + hd * 128 + 16 * kh;
        const f32x4 q0 = *(const f32x4*)qk, q1 = *(const f32x4*)(qk + 4);
        const f32x4 q2 = *(const f32x4*)(qk + 8), q3 = *(const f32x4*)(qk + 12);
        float sc = 0.f;
#pragma unroll
        for (int e = 0; e < 4; ++e) {
          sc += bf2f((unsigned short)s8a[e]) * q0[e] + bf2f((unsigned short)s8a[4 + e]) * q1[e];
          sc += bf2f((unsigned short)s8b[e]) * q2[e] + bf2f((unsigned short)s8b[4 + e]) * q3[e];
        }
        sc += __shfl_xor(sc, 1); sc += __shfl_xor(sc, 2); sc += __shfl_xor(sc, 4);
        if (kh == 0) {
          const float mn = fmaxf(mrun, sc);
          const float rf = __expf(mrun - mn);
          const float e = __expf(sc - mn);
          drun = drun * rf + e;
          mrun = mn;
          float2 fe = {rf, e};
          *(float2*)(sm + MSB + (rw * 4 + hd) * 8) = fe;
        }
      }
      bar_lds();
      {
        f32x4 tmp = splat4(0.f);
#pragma unroll
        for (int kk = 0; kk < 4; ++kk) {
          const short8 a = *(const short8*)(Hw + swz(l15, 64 * kk + 16 * l4));
          const short8 bv = *(const short8*)(ws + WV_OFF + (16 * w + l15) * 256 + 64 * kk + 16 * l4);
          tmp = __builtin_amdgcn_mfma_f32_16x16x32_bf16(a, bv, tmp, 0, 0, 0);
        }
#pragma unroll
        for (int r = 0; r < 4; ++r) {
          const float2 fe = *(const float2*)(sm + MSB + ((4 * l4 + r) * 4 + (w >> 1)) * 8);
          ctx[r] = ctx[r] * fe.x + fe.y * tmp[r];
        }
      }
    }
  }
  // h13 in MH0

  {  // daily heads
    const int r = tid >> 5, qq = tid & 31, q = qq & 15, hd = qq >> 4;
    const short8 h8 = *(const short8*)(sm + MH0 + swz(r, 16 * q));
    const float* wp = hd ? sig_w : mu_w;
    float s = 0.f;
#pragma unroll
    for (int e = 0; e < 8; ++e) s += bf2f((unsigned short)h8[e]) * wp[8 * q + e];
    s += __shfl_xor(s, 1); s += __shfl_xor(s, 2); s += __shfl_xor(s, 4); s += __shfl_xor(s, 8);
    if (q == 0) {
      if (hd) out[B_TOT + blkrow + r] = softplusf_(s + sig_b[0]);
      else    out[blkrow + r] = s + mu_b[0];
    }
  }
  if ((tid & 7) == 0) {
    const int rw = tid >> 5, hd = (tid >> 3) & 3;
    *(float*)(sm + MMD + (rw * 4 + hd) * 4) = drun;
  }
  __syncthreads();
  {  // finalize ctx -> bf16 tile MXB
    const float pb = pool_bin[256 + 16 * w + l15];
#pragma unroll
    for (int r = 0; r < 4; ++r) {
      const float d = *(const float*)(sm + MMD + ((4 * l4 + r) * 4 + (w >> 1)) * 4);
      const float v = ctx[r] * __builtin_amdgcn_rcpf(d) + pb;
      *(unsigned short*)(sm + MXB + swz(4 * l4 + r, 2 * (16 * w + l15))) = f2bf(v);
    }
  }
  __syncthreads();
  {  // monthly token = ctx@wout.T + bout -> MH1
    f32x4 oa = splat4(pool_bout[16 * w + l15]);
#pragma unroll
    for (int kk = 0; kk < 4; ++kk) {
      const short8 a = *(const short8*)(sm + MXB + swz(l15, 64 * kk + 16 * l4));
      const short8 bo = *(const short8*)(ws + WOUT_OFF + (16 * w + l15) * 256 + 64 * kk + 16 * l4);
      oa = __builtin_amdgcn_mfma_f32_16x16x32_bf16(a, bo, oa, 0, 0, 0);
    }
#pragma unroll
    for (int r = 0; r < 4; ++r)
      *(unsigned short*)(sm + MH1 + swz(4 * l4 + r, 2 * (16 * w + l15))) = f2bf(oa[r]);
  }
  __syncthreads();
  {  // token -> ws (coalesced)
    const size_t blkid = (size_t)(base >> 4) + blockIdx.x;
    *(uint2*)(ws + TOK_OFF + blkid * 4096 + tid * 8) = *(const uint2*)(sm + MH1 + tid * 8);
  }
}

// ===================== decoder kernel: 30 steps; outputs staged in LDS, one coalesced flush =====================
__global__ __launch_bounds__(512, 4)
void hfn_dec(const float* __restrict__ dmu_b_p, const float* __restrict__ dsig_b_p,
             char* __restrict__ ws, float* __restrict__ out) {
  __shared__ __align__(16) char sm[12288];
  const int tid = threadIdx.x;
  const int w = tid >> 6, lane = tid & 63, l15 = lane & 15, l4 = lane >> 4;
  const int blkrow = blockIdx.x << 4;

  // token -> MH1 (preserves swizzled layout)
  *(uint2*)(sm + 4096 + tid * 8) = *(const uint2*)(ws + TOK_OFF + (size_t)blockIdx.x * 4096 + tid * 8);

  short8 bhh[4][4];
  float bias_s[4];
#pragma unroll
  for (int g = 0; g < 4; ++g) {
    bias_s[g] = *(const float*)(ws + DB_OFF + 4 * (g * 128 + 16 * w + l15));
#pragma unroll
    for (int kk = 0; kk < 4; ++kk)
      bhh[g][kk] = *(const short8*)(ws + DWHH_OFF + (g * 128 + 16 * w + l15) * 256 + 64 * kk + 16 * l4);
  }
  short8 bh8[4];  // head B-tile frags (row0=dmu,row1=dsig)
#pragma unroll
  for (int kk = 0; kk < 4; ++kk)
    bh8[kk] = *(const short8*)(ws + DHW_OFF + l15 * 256 + 64 * kk + 16 * l4);
  const float hinit = (l15 == 0) ? dmu_b_p[0] : ((l15 == 1) ? dsig_b_p[0] : 0.f);
  float creg[4];
#pragma unroll
  for (int r = 0; r < 4; ++r) creg[r] = 0.f;
  __syncthreads();

  for (int t = 0; t < NSTEPS; ++t) {
    char* Hr = sm + (((t + 1) & 1) ? 4096 : 0);   // t=0 -> MH1 (token)
    char* Hw = sm + ((t & 1) ? 4096 : 0);
    f32x4 acc[4];
#pragma unroll
    for (int g = 0; g < 4; ++g) acc[g] = splat4(bias_s[g]);
#pragma unroll
    for (int kk = 0; kk < 4; ++kk) {
      const short8 a = *(const short8*)(Hr + swz(l15, 64 * kk + 16 * l4));
#pragma unroll
      for (int g = 0; g < 4; ++g)
        acc[g] = __builtin_amdgcn_mfma_f32_16x16x32_bf16(a, bhh[g][kk], acc[g], 0, 0, 0);
    }
#pragma unroll
    for (int r = 0; r < 4; ++r) {
      const float cn = sigmf_(acc[1][r]) * creg[r] + sigmf_(acc[0][r]) * tanhf_(acc[2][r]);
      creg[r] = cn;
      *(unsigned short*)(Hw + swz(4 * l4 + r, 2 * (16 * w + l15))) = f2bf(sigmf_(acc[3][r]) * tanhf_(cn));
    }
    if (t == 0) {  // x_t == h_t for t>=1: combined weights
#pragma unroll
      for (int g = 0; g < 4; ++g)
#pragma unroll
        for (int kk = 0; kk < 4; ++kk)
          bhh[g][kk] = *(const short8*)(ws + WD_OFF + (g * 128 + 16 * w + l15) * 256 + 64 * kk + 16 * l4);
    }
    bar_lds();
    if (w == (t & 7)) {  // monthly heads via MFMA (rotating wave) -> LDS staging
      f32x4 hac = splat4(hinit);
#pragma unroll
      for (int kk = 0; kk < 4; ++kk) {
        const short8 a = *(const short8*)(Hw + swz(l15, 64 * kk + 16 * l4));
        hac = __builtin_amdgcn_mfma_f32_16x16x32_bf16(a, bh8[kk], hac, 0, 0, 0);
      }
      if (l15 < 2)  // mu rows at DMOUT, sig raw at DMOUT+1920; [t][row] f32
        *(f32x4*)(sm + DMOUT + l15 * 1920 + (t * 16 + 4 * l4) * 4) = hac;
    }
  }
  __syncthreads();
  // coalesced flush: tid = row*30 + t exactly matches out layout
  if (tid < 480) {
    const int row = tid / 30, t = tid - row * 30;
    out[2 * B_TOT + (size_t)blkrow * 30 + tid] = *(const float*)(sm + DMOUT + (t * 16 + row) * 4);
    out[32 * B_TOT + (size_t)blkrow * 30 + tid] =
        softplusf_(*(const float*)(sm + DMOUT + 1920 + (t * 16 + row) * 4));
  }
}

extern "C" void kernel_launch(void* const* d_in, const int* in_sizes, int n_in,
                              void* d_out, int out_size, void* d_ws, size_t ws_size,
                              hipStream_t stream) {
  (void)in_sizes; (void)n_in; (void)out_size;
  const float* x14      = (const float*)d_in[0];
  const float* fa_w     = (const float*)d_in[1];
  const float* fa_b     = (const float*)d_in[2];
  const float* enc_wih  = (const float*)d_in[3];
  const float* enc_whh  = (const float*)d_in[4];
  const float* enc_bih  = (const float*)d_in[5];
  const float* enc_bhh  = (const float*)d_in[6];
  const float* q_tok    = (const float*)d_in[7];
  const float* pool_win = (const float*)d_in[8];
  const float* pool_bin = (const float*)d_in[9];
  const float* pool_wout= (const float*)d_in[10];
  const float* pool_bout= (const float*)d_in[11];
  const float* mu_w     = (const float*)d_in[12];
  const float* mu_b     = (const float*)d_in[13];
  const float* sig_w    = (const float*)d_in[14];
  const float* sig_b    = (const float*)d_in[15];
  const float* dec_wih  = (const float*)d_in[16];
  const float* dec_whh  = (const float*)d_in[17];
  const float* dec_bih  = (const float*)d_in[18];
  const float* dec_bhh  = (const float*)d_in[19];
  const float* dmu_w    = (const float*)d_in[20];
  const float* dmu_b    = (const float*)d_in[21];
  const float* dsig_w   = (const float*)d_in[22];
  const float* dsig_b   = (const float*)d_in[23];
  char* ws = (char*)d_ws;

  hfn_prep<<<dim3(128), dim3(256), 0, stream>>>(fa_w, enc_wih, enc_whh, enc_bih, enc_bhh,
      q_tok, pool_win, pool_bin, pool_wout, dec_wih, dec_whh, dec_bih, dec_bhh,
      dmu_w, dsig_w, ws);

  // chunk rows so g_in slots fit ws; rows per chunk multiple of 64
  size_t avail = ws_size > (size_t)GIN_OFF ? ws_size - (size_t)GIN_OFF : 0;
  long nslots = (long)(avail / SLOT_BYTES);
  int chrows = (int)((nslots * 16) / 64) * 64;
  if (chrows > B_TOT) chrows = B_TOT;
  if (chrows < 64) chrows = 64;
  for (int base = 0; base < B_TOT; base += chrows) {
    const int rows = (B_TOT - base < chrows) ? (B_TOT - base) : chrows;
    hfn_pre2<<<dim3(rows / 64, NDW), dim3(256), 0, stream>>>(x14, fa_b, ws, base);
    hfn_enc<<<dim3(rows / 16), dim3(512), 0, stream>>>(pool_bin, pool_bout,
        mu_w, mu_b, sig_w, sig_b, ws, (float*)d_out, base);
  }
  hfn_dec<<<dim3(2048), dim3(512), 0, stream>>>(dmu_b, dsig_b, ws, (float*)d_out);
}

// Round 10
// 832.428 us; speedup vs baseline: 1.4398x; 1.4398x over previous
//
#include <hip/hip_runtime.h>

#define B_TOT 32768
#define NDW 14
#define NSTEPS 30

typedef __attribute__((ext_vector_type(8))) short short8;
typedef __attribute__((ext_vector_type(4))) float f32x4;
typedef __attribute__((ext_vector_type(2))) unsigned int uint2v;

// ---- workspace byte offsets ----
#define WIH_OFF   0           // enc_wih bf16 plain [512][128]
#define WHH_OFF   131072      // enc_whh bf16 plain [512][128]
#define WD_OFF    262144      // dec_wih+dec_whh bf16 plain [512][128]
#define DWHH_OFF  393216      // dec_whh bf16 plain [512][128]
#define FAW_OFF   524288      // fa_w bf16 plain [128][128]
#define WV_OFF    557056      // pooling wv bf16 plain [128][128]
#define WOUT_OFF  589824      // pool_wout bf16 plain [128][128]
#define QK_OFF    622592      // folded q@wk / sqrt(dh), f32 [4][128]
#define EB_OFF    624640      // enc_bih+enc_bhh f32 [512]
#define DB_OFF    626688      // dec_bih+dec_bhh f32 [512]
#define DHW_OFF   628736      // decoder head B-tile bf16 [16][128] (row0=dmu,row1=dsig)
#define TOK_OFF   632832      // monthly token bf16 swizzled tiles [2048][4096]
#define GIN_OFF   9021440     // g_in slots
#define SLOT_BYTES (NDW * 16384)                  // 229376 per 16-row slot
// g_in tile (16 KiB per (slot,t)): 4 gate planes x 4 KiB; plane g pos p (0..511) holds
// 8B chunk (r0|r1<<16, r2|r3<<16); enc thread tid reads pos=tid of each plane.

// ---- enc kernel LDS (15 KiB) ----
#define MH0   0
#define MH1   4096
#define MSB   8192
#define MMD   8704
#define MXB   11264

// ---- dec kernel LDS (12 KiB) ----
#define DMOUT 8192

__device__ __forceinline__ unsigned short f2bf(float f) {
  unsigned int u = __float_as_uint(f);
  u += 0x7fffu + ((u >> 16) & 1u);
  return (unsigned short)(u >> 16);
}
__device__ __forceinline__ float bf2f(unsigned short h) {
  return __uint_as_float(((unsigned int)h) << 16);
}
__device__ __forceinline__ float sigmf_(float x) { return __builtin_amdgcn_rcpf(1.f + __expf(-x)); }
__device__ __forceinline__ float tanhf_(float x) { return 1.f - 2.f * __builtin_amdgcn_rcpf(1.f + __expf(2.f * x)); }
__device__ __forceinline__ float softplusf_(float x) { return x > 20.f ? x : __logf(1.f + __expf(x)); }
__device__ __forceinline__ int swz(int row, int bc) { return row * 256 + (bc ^ ((row & 7) << 4)); }
__device__ __forceinline__ f32x4 splat4(float v) { f32x4 r = {v, v, v, v}; return r; }
__device__ __forceinline__ void bar_lds() {
  asm volatile("s_waitcnt lgkmcnt(0)" ::: "memory");
  __builtin_amdgcn_s_barrier();
  __builtin_amdgcn_sched_barrier(0);
}

// ===================== prep: weight conversion / folding =====================
__global__ void hfn_prep(const float* __restrict__ fa_w,
                         const float* __restrict__ enc_wih, const float* __restrict__ enc_whh,
                         const float* __restrict__ enc_bih, const float* __restrict__ enc_bhh,
                         const float* __restrict__ q_tok,
                         const float* __restrict__ pool_win, const float* __restrict__ pool_bin,
                         const float* __restrict__ pool_wout,
                         const float* __restrict__ dec_wih, const float* __restrict__ dec_whh,
                         const float* __restrict__ dec_bih, const float* __restrict__ dec_bhh,
                         const float* __restrict__ dmu_w, const float* __restrict__ dsig_w,
                         char* __restrict__ ws) {
  const int gt = blockIdx.x * 256 + threadIdx.x;
  const int gs = gridDim.x * 256;
  for (int i = gt; i < 65536; i += gs) *(unsigned short*)(ws + WIH_OFF + 2 * i) = f2bf(enc_wih[i]);
  for (int i = gt; i < 65536; i += gs) *(unsigned short*)(ws + WHH_OFF + 2 * i) = f2bf(enc_whh[i]);
  for (int i = gt; i < 65536; i += gs) *(unsigned short*)(ws + WD_OFF + 2 * i) = f2bf(dec_wih[i] + dec_whh[i]);
  for (int i = gt; i < 65536; i += gs) *(unsigned short*)(ws + DWHH_OFF + 2 * i) = f2bf(dec_whh[i]);
  for (int i = gt; i < 16384; i += gs) *(unsigned short*)(ws + FAW_OFF + 2 * i) = f2bf(fa_w[i]);
  for (int i = gt; i < 16384; i += gs) *(unsigned short*)(ws + WV_OFF + 2 * i) = f2bf(pool_win[32768 + i]);
  for (int i = gt; i < 16384; i += gs) *(unsigned short*)(ws + WOUT_OFF + 2 * i) = f2bf(pool_wout[i]);
  for (int i = gt; i < 512; i += gs) *(float*)(ws + EB_OFF + 4 * i) = enc_bih[i] + enc_bhh[i];
  for (int i = gt; i < 512; i += gs) *(float*)(ws + DB_OFF + 4 * i) = dec_bih[i] + dec_bhh[i];
  for (int i = gt; i < 2048; i += gs) {  // decoder head B-tile
    const int row = i >> 7, k = i & 127;
    const float v = (row == 0) ? dmu_w[k] : ((row == 1) ? dsig_w[k] : 0.f);
    *(unsigned short*)(ws + DHW_OFF + 2 * i) = f2bf(v);
  }
  if (blockIdx.x == 0) {
    __shared__ float q[128];
    const int t = threadIdx.x;
    if (t < 128) {
      float a = 0.f;
      for (int k = 0; k < 128; ++k) a += q_tok[k] * pool_win[t * 128 + k];
      q[t] = a + pool_bin[t];
    }
    __syncthreads();
    for (int j = t; j < 512; j += 256) {
      const int h = j >> 7, kc = j & 127;
      float a = 0.f;
      for (int d = 0; d < 32; ++d) a += q[32 * h + d] * pool_win[(128 + 32 * h + d) * 128 + kc];
      *(float*)(ws + QK_OFF + 4 * j) = a * 0.17677669529663687f;  // bk dropped (softmax-invariant)
    }
  }
}

// ===================== pre-pass v3: 128 rows x ALL 14 t per block (weights amortized 14x) ====
// 512 thr / 8 waves; wave w: attention rows [16w,16w+16); gates: gate g=w>>1, col-blocks
// ntg=(w&1)*4+0..3 (WIH quarter-plane resident in 64 VGPRs). FAW staged once in LDS.
// x double-buffered in LDS; x(t+1) issued to regs before gates, written to LDS after (T14).
__global__ __launch_bounds__(512, 2)
void hfn_pre3(const float* __restrict__ x14, const float* __restrict__ fa_b,
              char* __restrict__ ws, int base) {
  __shared__ __align__(16) char sm[98304];  // FAW 32K | xbuf0 32K | xbuf1 32K
  const int tid = threadIdx.x;
  const int w = tid >> 6, lane = tid & 63, l15 = lane & 15, l4 = lane >> 4;
  const int bx = blockIdx.x;
  const int row0 = base + (bx << 7);
  const int g = w >> 1;
  const int xr = tid >> 2, xq = tid & 3;

  {  // stage FAW plain ws -> swizzled LDS (once per block)
    const char* src = ws + FAW_OFF + xr * 256 + 64 * xq;
#pragma unroll
    for (int c = 0; c < 4; ++c)
      *(f32x4*)(sm + swz(xr, 64 * xq + 16 * c)) = *(const f32x4*)(src + 16 * c);
  }
  short8 bw[4][4];  // WIH quarter-plane, resident
  float eb4[4];
#pragma unroll
  for (int nt = 0; nt < 4; ++nt) {
    const int gcb = g * 128 + (w & 1) * 64 + 16 * nt;
    eb4[nt] = *(const float*)(ws + EB_OFF + 4 * (gcb + l15));
#pragma unroll
    for (int kk = 0; kk < 4; ++kk)
      bw[nt][kk] = *(const short8*)(ws + WIH_OFF + (gcb + l15) * 256 + 64 * kk + 16 * l4);
  }
  float fbias[8];
#pragma unroll
  for (int nt = 0; nt < 8; ++nt) fbias[nt] = fa_b[16 * nt + l15];
  {  // stage x(0) -> buf0
    const float* src = x14 + ((size_t)(row0 + xr) * NDW) * 128 + 32 * xq;
#pragma unroll
    for (int c = 0; c < 4; ++c) {
      f32x4 v0 = __builtin_nontemporal_load((const f32x4*)(src + 8 * c));
      f32x4 v1 = __builtin_nontemporal_load((const f32x4*)(src + 8 * c + 4));
      short8 s;
#pragma unroll
      for (int e = 0; e < 4; ++e) { s[e] = (short)f2bf(v0[e]); s[e + 4] = (short)f2bf(v1[e]); }
      *(short8*)(sm + 32768 + swz(xr, 64 * xq + 16 * c)) = s;
    }
  }
  __syncthreads();

  for (int t = 0; t < NDW; ++t) {
    char* bufc = sm + 32768 + (t & 1) * 32768;
    char* bufn = sm + 32768 + ((t + 1) & 1) * 32768;
    {  // attention in place on bufc: wave w handles rows [16w, 16w+16); FAW from LDS
      f32x4 patt[8];
#pragma unroll
      for (int nt = 0; nt < 8; ++nt) patt[nt] = splat4(fbias[nt]);
#pragma unroll
      for (int kk = 0; kk < 4; ++kk) {
        const short8 a = *(const short8*)(bufc + swz(16 * w + l15, 64 * kk + 16 * l4));
#pragma unroll
        for (int nt = 0; nt < 8; ++nt) {
          const short8 b = *(const short8*)(sm + swz(16 * nt + l15, 64 * kk + 16 * l4));
          patt[nt] = __builtin_amdgcn_mfma_f32_16x16x32_bf16(a, b, patt[nt], 0, 0, 0);
        }
      }
#pragma unroll
      for (int r = 0; r < 4; ++r) {
        float m = patt[0][r];
#pragma unroll
        for (int nt = 1; nt < 8; ++nt) m = fmaxf(m, patt[nt][r]);
        m = fmaxf(m, __shfl_xor(m, 1)); m = fmaxf(m, __shfl_xor(m, 2));
        m = fmaxf(m, __shfl_xor(m, 4)); m = fmaxf(m, __shfl_xor(m, 8));
        float s = 0.f;
#pragma unroll
        for (int nt = 0; nt < 8; ++nt) { const float e = __expf(patt[nt][r] - m); patt[nt][r] = e; s += e; }
        s += __shfl_xor(s, 1); s += __shfl_xor(s, 2); s += __shfl_xor(s, 4); s += __shfl_xor(s, 8);
        const float rs = __builtin_amdgcn_rcpf(s);
        const int row = 16 * w + 4 * l4 + r;
#pragma unroll
        for (int nt = 0; nt < 8; ++nt) {
          const int ad = swz(row, 2 * (16 * nt + l15));
          const float xv = bf2f(*(const unsigned short*)(bufc + ad));
          *(unsigned short*)(bufc + ad) = f2bf(patt[nt][r] * rs * xv);
        }
      }
    }
    __syncthreads();  // xw ready for all waves
    // issue x(t+1) loads early (held in regs; hides under gates MFMAs)
    f32x4 xv[8];
    if (t < NDW - 1) {
      const float* src = x14 + ((size_t)(row0 + xr) * NDW + t + 1) * 128 + 32 * xq;
#pragma unroll
      for (int c = 0; c < 4; ++c) {
        xv[2 * c] = __builtin_nontemporal_load((const f32x4*)(src + 8 * c));
        xv[2 * c + 1] = __builtin_nontemporal_load((const f32x4*)(src + 8 * c + 4));
      }
    }
    // gates: 8 row-subtiles x 4 col-blocks; nontemporal 512B-contiguous wave stores
#pragma unroll 1
    for (int rt = 0; rt < 8; ++rt) {
      short8 a[4];
#pragma unroll
      for (int kk = 0; kk < 4; ++kk)
        a[kk] = *(const short8*)(bufc + swz(16 * rt + l15, 64 * kk + 16 * l4));
#pragma unroll
      for (int nt = 0; nt < 4; ++nt) {
        f32x4 acc = splat4(eb4[nt]);
#pragma unroll
        for (int kk = 0; kk < 4; ++kk)
          acc = __builtin_amdgcn_mfma_f32_16x16x32_bf16(a[kk], bw[nt][kk], acc, 0, 0, 0);
        uint2v pk;
        pk[0] = (unsigned int)f2bf(acc[0]) | ((unsigned int)f2bf(acc[1]) << 16);
        pk[1] = (unsigned int)f2bf(acc[2]) | ((unsigned int)f2bf(acc[3]) << 16);
        const int ntg = (w & 1) * 4 + nt;
        char* dst = ws + GIN_OFF + (size_t)(8 * bx + rt) * SLOT_BYTES + t * 16384
                  + (g << 12) + (((ntg << 6) + (l4 << 4) + l15) << 3);
        __builtin_nontemporal_store(pk, (uint2v*)dst);
      }
    }
    // write x(t+1) regs -> bufn
    if (t < NDW - 1) {
#pragma unroll
      for (int c = 0; c < 4; ++c) {
        short8 s;
#pragma unroll
        for (int e = 0; e < 4; ++e) {
          s[e] = (short)f2bf(xv[2 * c][e]);
          s[e + 4] = (short)f2bf(xv[2 * c + 1][e]);
        }
        *(short8*)(bufn + swz(xr, 64 * xq + 16 * c)) = s;
      }
    }
    __syncthreads();  // bufn staged; bufc reads done
  }
}

// ===================== encoder kernel: 14 steps + online pooling + daily heads + token =====================
__global__ __launch_bounds__(512, 4)
void hfn_enc(const float* __restrict__ pool_bin, const float* __restrict__ pool_bout,
             const float* __restrict__ mu_w, const float* __restrict__ mu_b,
             const float* __restrict__ sig_w, const float* __restrict__ sig_b,
             char* __restrict__ ws, float* __restrict__ out, int base) {
  __shared__ __align__(16) char sm[15360];
  const int tid = threadIdx.x;
  const int w = tid >> 6, lane = tid & 63, l15 = lane & 15, l4 = lane >> 4;
  const int blkrow = base + (blockIdx.x << 4);

  short8 bhh[4][4];
#pragma unroll
  for (int g = 0; g < 4; ++g)
#pragma unroll
    for (int kk = 0; kk < 4; ++kk)
      bhh[g][kk] = *(const short8*)(ws + WHH_OFF + (g * 128 + 16 * w + l15) * 256 + 64 * kk + 16 * l4);
  float creg[4];
#pragma unroll
  for (int r = 0; r < 4; ++r) creg[r] = 0.f;
  *(uint2*)(sm + MH0 + tid * 8) = make_uint2(0, 0);  // h_{-1} = 0

  const char* ginb = ws + GIN_OFF + (size_t)blockIdx.x * SLOT_BYTES + tid * 8;
  uint2 gp0 = *(const uint2*)(ginb);            // prefetch t=0, planes 0..3
  uint2 gp1 = *(const uint2*)(ginb + 4096);
  uint2 gp2 = *(const uint2*)(ginb + 8192);
  uint2 gp3 = *(const uint2*)(ginb + 12288);
  float mrun = -1e30f, drun = 0.f;
  f32x4 ctx = splat4(0.f);
  bar_lds();

  for (int t = 0; t < NDW; ++t) {
    char* Hr = sm + ((t & 1) ? MH1 : MH0);
    char* Hw = sm + ((t & 1) ? MH0 : MH1);
    const uint2 gc0 = gp0, gc1 = gp1, gc2 = gp2, gc3 = gp3;
    if (t < NDW - 1) {  // prefetch next t; stays in flight across bar_lds
      const char* nb = ginb + (t + 1) * 16384;
      gp0 = *(const uint2*)(nb);
      gp1 = *(const uint2*)(nb + 4096);
      gp2 = *(const uint2*)(nb + 8192);
      gp3 = *(const uint2*)(nb + 12288);
    }
    f32x4 acc[4];
    acc[0][0] = bf2f((unsigned short)(gc0.x & 0xffff)); acc[0][1] = bf2f((unsigned short)(gc0.x >> 16));
    acc[0][2] = bf2f((unsigned short)(gc0.y & 0xffff)); acc[0][3] = bf2f((unsigned short)(gc0.y >> 16));
    acc[1][0] = bf2f((unsigned short)(gc1.x & 0xffff)); acc[1][1] = bf2f((unsigned short)(gc1.x >> 16));
    acc[1][2] = bf2f((unsigned short)(gc1.y & 0xffff)); acc[1][3] = bf2f((unsigned short)(gc1.y >> 16));
    acc[2][0] = bf2f((unsigned short)(gc2.x & 0xffff)); acc[2][1] = bf2f((unsigned short)(gc2.x >> 16));
    acc[2][2] = bf2f((unsigned short)(gc2.y & 0xffff)); acc[2][3] = bf2f((unsigned short)(gc2.y >> 16));
    acc[3][0] = bf2f((unsigned short)(gc3.x & 0xffff)); acc[3][1] = bf2f((unsigned short)(gc3.x >> 16));
    acc[3][2] = bf2f((unsigned short)(gc3.y & 0xffff)); acc[3][3] = bf2f((unsigned short)(gc3.y >> 16));
#pragma unroll
    for (int kk = 0; kk < 4; ++kk) {
      const short8 a = *(const short8*)(Hr + swz(l15, 64 * kk + 16 * l4));
#pragma unroll
      for (int g = 0; g < 4; ++g)
        acc[g] = __builtin_amdgcn_mfma_f32_16x16x32_bf16(a, bhh[g][kk], acc[g], 0, 0, 0);
    }
#pragma unroll
    for (int r = 0; r < 4; ++r) {
      const float cn = sigmf_(acc[1][r]) * creg[r] + sigmf_(acc[0][r]) * tanhf_(acc[2][r]);
      creg[r] = cn;
      *(unsigned short*)(Hw + swz(4 * l4 + r, 2 * (16 * w + l15))) = f2bf(sigmf_(acc[3][r]) * tanhf_(cn));
    }
    bar_lds();
    if (t >= 7) {  // online-softmax pooling update on h_t
      {
        const int rw = tid >> 5, hd = (tid >> 3) & 3, kh = tid & 7;
        const short8 s8a = *(const short8*)(Hw + swz(rw, 32 * kh));
        const short8 s8b = *(const short8*)(Hw + swz(rw, 32 * kh + 16));
        const float* qk = (const float*)(ws + QK_OFF) + hd * 128 + 16 * kh;
        const f32x4 q0 = *(const f32x4*)qk, q1 = *(const f32x4*)(qk + 4);
        const f32x4 q2 = *(const f32x4*)(qk + 8), q3 = *(const f32x4*)(qk + 12);
        float sc = 0.f;
#pragma unroll
        for (int e = 0; e < 4; ++e) {
          sc += bf2f((unsigned short)s8a[e]) * q0[e] + bf2f((unsigned short)s8a[4 + e]) * q1[e];
          sc += bf2f((unsigned short)s8b[e]) * q2[e] + bf2f((unsigned short)s8b[4 + e]) * q3[e];
        }
        sc += __shfl_xor(sc, 1); sc += __shfl_xor(sc, 2); sc += __shfl_xor(sc, 4);
        if (kh == 0) {
          const float mn = fmaxf(mrun, sc);
          const float rf = __expf(mrun - mn);
          const float e = __expf(sc - mn);
          drun = drun * rf + e;
          mrun = mn;
          float2 fe = {rf, e};
          *(float2*)(sm + MSB + (rw * 4 + hd) * 8) = fe;
        }
      }
      bar_lds();
      {
        f32x4 tmp = splat4(0.f);
#pragma unroll
        for (int kk = 0; kk < 4; ++kk) {
          const short8 a = *(const short8*)(Hw + swz(l15, 64 * kk + 16 * l4));
          const short8 bv = *(const short8*)(ws + WV_OFF + (16 * w + l15) * 256 + 64 * kk + 16 * l4);
          tmp = __builtin_amdgcn_mfma_f32_16x16x32_bf16(a, bv, tmp, 0, 0, 0);
        }
#pragma unroll
        for (int r = 0; r < 4; ++r) {
          const float2 fe = *(const float2*)(sm + MSB + ((4 * l4 + r) * 4 + (w >> 1)) * 8);
          ctx[r] = ctx[r] * fe.x + fe.y * tmp[r];
        }
      }
    }
  }
  // h13 in MH0

  {  // daily heads
    const int r = tid >> 5, qq = tid & 31, q = qq & 15, hd = qq >> 4;
    const short8 h8 = *(const short8*)(sm + MH0 + swz(r, 16 * q));
    const float* wp = hd ? sig_w : mu_w;
    float s = 0.f;
#pragma unroll
    for (int e = 0; e < 8; ++e) s += bf2f((unsigned short)h8[e]) * wp[8 * q + e];
    s += __shfl_xor(s, 1); s += __shfl_xor(s, 2); s += __shfl_xor(s, 4); s += __shfl_xor(s, 8);
    if (q == 0) {
      if (hd) out[B_TOT + blkrow + r] = softplusf_(s + sig_b[0]);
      else    out[blkrow + r] = s + mu_b[0];
    }
  }
  if ((tid & 7) == 0) {
    const int rw = tid >> 5, hd = (tid >> 3) & 3;
    *(float*)(sm + MMD + (rw * 4 + hd) * 4) = drun;
  }
  __syncthreads();
  {  // finalize ctx -> bf16 tile MXB
    const float pb = pool_bin[256 + 16 * w + l15];
#pragma unroll
    for (int r = 0; r < 4; ++r) {
      const float d = *(const float*)(sm + MMD + ((4 * l4 + r) * 4 + (w >> 1)) * 4);
      const float v = ctx[r] * __builtin_amdgcn_rcpf(d) + pb;
      *(unsigned short*)(sm + MXB + swz(4 * l4 + r, 2 * (16 * w + l15))) = f2bf(v);
    }
  }
  __syncthreads();
  {  // monthly token = ctx@wout.T + bout -> MH1
    f32x4 oa = splat4(pool_bout[16 * w + l15]);
#pragma unroll
    for (int kk = 0; kk < 4; ++kk) {
      const short8 a = *(const short8*)(sm + MXB + swz(l15, 64 * kk + 16 * l4));
      const short8 bo = *(const short8*)(ws + WOUT_OFF + (16 * w + l15) * 256 + 64 * kk + 16 * l4);
      oa = __builtin_amdgcn_mfma_f32_16x16x32_bf16(a, bo, oa, 0, 0, 0);
    }
#pragma unroll
    for (int r = 0; r < 4; ++r)
      *(unsigned short*)(sm + MH1 + swz(4 * l4 + r, 2 * (16 * w + l15))) = f2bf(oa[r]);
  }
  __syncthreads();
  {  // token -> ws (coalesced)
    const size_t blkid = (size_t)(base >> 4) + blockIdx.x;
    *(uint2*)(ws + TOK_OFF + blkid * 4096 + tid * 8) = *(const uint2*)(sm + MH1 + tid * 8);
  }
}

// ===================== decoder kernel: 30 steps; outputs staged in LDS, one coalesced flush =====================
__global__ __launch_bounds__(512, 4)
void hfn_dec(const float* __restrict__ dmu_b_p, const float* __restrict__ dsig_b_p,
             char* __restrict__ ws, float* __restrict__ out) {
  __shared__ __align__(16) char sm[12288];
  const int tid = threadIdx.x;
  const int w = tid >> 6, lane = tid & 63, l15 = lane & 15, l4 = lane >> 4;
  const int blkrow = blockIdx.x << 4;

  *(uint2*)(sm + 4096 + tid * 8) = *(const uint2*)(ws + TOK_OFF + (size_t)blockIdx.x * 4096 + tid * 8);

  short8 bhh[4][4];
  float bias_s[4];
#pragma unroll
  for (int g = 0; g < 4; ++g) {
    bias_s[g] = *(const float*)(ws + DB_OFF + 4 * (g * 128 + 16 * w + l15));
#pragma unroll
    for (int kk = 0; kk < 4; ++kk)
      bhh[g][kk] = *(const short8*)(ws + DWHH_OFF + (g * 128 + 16 * w + l15) * 256 + 64 * kk + 16 * l4);
  }
  short8 bh8[4];  // head B-tile frags (row0=dmu,row1=dsig)
#pragma unroll
  for (int kk = 0; kk < 4; ++kk)
    bh8[kk] = *(const short8*)(ws + DHW_OFF + l15 * 256 + 64 * kk + 16 * l4);
  const float hinit = (l15 == 0) ? dmu_b_p[0] : ((l15 == 1) ? dsig_b_p[0] : 0.f);
  float creg[4];
#pragma unroll
  for (int r = 0; r < 4; ++r) creg[r] = 0.f;
  __syncthreads();

  for (int t = 0; t < NSTEPS; ++t) {
    char* Hr = sm + (((t + 1) & 1) ? 4096 : 0);   // t=0 -> MH1 (token)
    char* Hw = sm + ((t & 1) ? 4096 : 0);
    f32x4 acc[4];
#pragma unroll
    for (int g = 0; g < 4; ++g) acc[g] = splat4(bias_s[g]);
#pragma unroll
    for (int kk = 0; kk < 4; ++kk) {
      const short8 a = *(const short8*)(Hr + swz(l15, 64 * kk + 16 * l4));
#pragma unroll
      for (int g = 0; g < 4; ++g)
        acc[g] = __builtin_amdgcn_mfma_f32_16x16x32_bf16(a, bhh[g][kk], acc[g], 0, 0, 0);
    }
#pragma unroll
    for (int r = 0; r < 4; ++r) {
      const float cn = sigmf_(acc[1][r]) * creg[r] + sigmf_(acc[0][r]) * tanhf_(acc[2][r]);
      creg[r] = cn;
      *(unsigned short*)(Hw + swz(4 * l4 + r, 2 * (16 * w + l15))) = f2bf(sigmf_(acc[3][r]) * tanhf_(cn));
    }
    if (t == 0) {  // x_t == h_t for t>=1: combined weights
#pragma unroll
      for (int g = 0; g < 4; ++g)
#pragma unroll
        for (int kk = 0; kk < 4; ++kk)
          bhh[g][kk] = *(const short8*)(ws + WD_OFF + (g * 128 + 16 * w + l15) * 256 + 64 * kk + 16 * l4);
    }
    bar_lds();
    if (w == (t & 7)) {  // monthly heads via MFMA (rotating wave) -> LDS staging
      f32x4 hac = splat4(hinit);
#pragma unroll
      for (int kk = 0; kk < 4; ++kk) {
        const short8 a = *(const short8*)(Hw + swz(l15, 64 * kk + 16 * l4));
        hac = __builtin_amdgcn_mfma_f32_16x16x32_bf16(a, bh8[kk], hac, 0, 0, 0);
      }
      if (l15 < 2)  // mu rows at DMOUT, sig raw at DMOUT+1920; [t][row] f32
        *(f32x4*)(sm + DMOUT + l15 * 1920 + (t * 16 + 4 * l4) * 4) = hac;
    }
  }
  __syncthreads();
  if (tid < 480) {  // coalesced flush: tid = row*30 + t matches out layout
    const int row = tid / 30, t = tid - row * 30;
    out[2 * B_TOT + (size_t)blkrow * 30 + tid] = *(const float*)(sm + DMOUT + (t * 16 + row) * 4);
    out[32 * B_TOT + (size_t)blkrow * 30 + tid] =
        softplusf_(*(const float*)(sm + DMOUT + 1920 + (t * 16 + row) * 4));
  }
}

extern "C" void kernel_launch(void* const* d_in, const int* in_sizes, int n_in,
                              void* d_out, int out_size, void* d_ws, size_t ws_size,
                              hipStream_t stream) {
  (void)in_sizes; (void)n_in; (void)out_size;
  const float* x14      = (const float*)d_in[0];
  const float* fa_w     = (const float*)d_in[1];
  const float* fa_b     = (const float*)d_in[2];
  const float* enc_wih  = (const float*)d_in[3];
  const float* enc_whh  = (const float*)d_in[4];
  const float* enc_bih  = (const float*)d_in[5];
  const float* enc_bhh  = (const float*)d_in[6];
  const float* q_tok    = (const float*)d_in[7];
  const float* pool_win = (const float*)d_in[8];
  const float* pool_bin = (const float*)d_in[9];
  const float* pool_wout= (const float*)d_in[10];
  const float* pool_bout= (const float*)d_in[11];
  const float* mu_w     = (const float*)d_in[12];
  const float* mu_b     = (const float*)d_in[13];
  const float* sig_w    = (const float*)d_in[14];
  const float* sig_b    = (const float*)d_in[15];
  const float* dec_wih  = (const float*)d_in[16];
  const float* dec_whh  = (const float*)d_in[17];
  const float* dec_bih  = (const float*)d_in[18];
  const float* dec_bhh  = (const float*)d_in[19];
  const float* dmu_w    = (const float*)d_in[20];
  const float* dmu_b    = (const float*)d_in[21];
  const float* dsig_w   = (const float*)d_in[22];
  const float* dsig_b   = (const float*)d_in[23];
  char* ws = (char*)d_ws;

  hfn_prep<<<dim3(128), dim3(256), 0, stream>>>(fa_w, enc_wih, enc_whh, enc_bih, enc_bhh,
      q_tok, pool_win, pool_bin, pool_wout, dec_wih, dec_whh, dec_bih, dec_bhh,
      dmu_w, dsig_w, ws);

  // chunk rows so g_in slots fit ws; rows per chunk multiple of 128
  size_t avail = ws_size > (size_t)GIN_OFF ? ws_size - (size_t)GIN_OFF : 0;
  long nslots = (long)(avail / SLOT_BYTES);
  int chrows = (int)((nslots * 16) / 128) * 128;
  if (chrows > B_TOT) chrows = B_TOT;
  if (chrows < 128) chrows = 128;
  for (int base = 0; base < B_TOT; base += chrows) {
    const int rows = (B_TOT - base < chrows) ? (B_TOT - base) : chrows;
    hfn_pre3<<<dim3(rows / 128), dim3(512), 0, stream>>>(x14, fa_b, ws, base);
    hfn_enc<<<dim3(rows / 16), dim3(512), 0, stream>>>(pool_bin, pool_bout,
        mu_w, mu_b, sig_w, sig_b, ws, (float*)d_out, base);
  }
  hfn_dec<<<dim3(2048), dim3(512), 0, stream>>>(dmu_b, dsig_b, ws, (float*)d_out);
}